// Round 1
// 217.778 us; speedup vs baseline: 1.0049x; 1.0049x over previous
//
#include <hip/hip_runtime.h>

#define CLASS_NUM 19
#define NBINS (CLASS_NUM * CLASS_NUM)   // 361
#define HW (512 * 512)                  // 262144
#define NPIX (8 * HW)                   // 2097152
#define NVEC (NPIX / 4)                 // 524288 pixel-quads
#define HWV (HW / 4)                    // 65536 float4 per channel-image
#define QPT 4                           // pixel-quads per thread
#define TPB 512                         // threads per block
#define TILE (TPB * QPT)                // 2048 quads per block
#define NBLK (NVEC / TILE)              // 256 blocks

typedef float f4 __attribute__((ext_vector_type(4)));

// Kernel 0: overwrite the 361-int output's 0xAA poison with zeros so the
// histogram kernel can accumulate into it directly. One tiny dispatch.
__global__ void zero_out_kernel(int* __restrict__ out) {
    if (threadIdx.x < NBINS) out[threadIdx.x] = 0;
}

// Kernel 1: 256 blocks x 512 threads; each thread handles 4 pixel-quads TPB
// apart (32 KB contiguous per-channel block footprint -> DRAM burst locality).
// Per-block LDS histogram, then DIRECT device-scope atomicAdd into out.
// NOTE: d_ws is deliberately unused — the harness's 608 MiB workspace
// re-poison fills (~187 us/iter, 2x93.5 us in rocprof) dwarfed the ~30 us
// of real work. No ws use -> no ws poison cost (hypothesis under test).
__global__ __launch_bounds__(TPB, 2) void confusion_kernel(
    const f4*   __restrict__ in,   // [B, C, HWV]
    const int4* __restrict__ tgt,  // [B, HWV] as int4
    int* __restrict__ out)         // [361], pre-zeroed by zero_out_kernel
{
    __shared__ int hist[NBINS];
    for (int i = threadIdx.x; i < NBINS; i += TPB) hist[i] = 0;
    __syncthreads();

    const int g0 = blockIdx.x * TILE + threadIdx.x;
    const int b  = g0 >> 16;                          // image idx (same for all 4 quads)
    const int h0 = g0 & (HWV - 1);
    const f4* p  = in + (size_t)b * (CLASS_NUM * HWV) + h0;

    const int4 t0 = tgt[g0];
    const int4 t1 = tgt[g0 + TPB];
    const int4 t2 = tgt[g0 + 2 * TPB];
    const int4 t3 = tgt[g0 + 3 * TPB];

    f4 best0 = __builtin_nontemporal_load(p);
    f4 best1 = __builtin_nontemporal_load(p + TPB);
    f4 best2 = __builtin_nontemporal_load(p + 2 * TPB);
    f4 best3 = __builtin_nontemporal_load(p + 3 * TPB);
    int i0x = 0, i0y = 0, i0z = 0, i0w = 0;
    int i1x = 0, i1y = 0, i1z = 0, i1w = 0;
    int i2x = 0, i2y = 0, i2z = 0, i2w = 0;
    int i3x = 0, i3y = 0, i3z = 0, i3w = 0;

    #pragma unroll
    for (int c = 1; c < CLASS_NUM; ++c) {
        const f4* q = p + (size_t)c * HWV;
        f4 v0 = __builtin_nontemporal_load(q);
        f4 v1 = __builtin_nontemporal_load(q + TPB);
        f4 v2 = __builtin_nontemporal_load(q + 2 * TPB);
        f4 v3 = __builtin_nontemporal_load(q + 3 * TPB);
        i0x = (v0.x > best0.x) ? c : i0x;  best0.x = fmaxf(best0.x, v0.x);
        i0y = (v0.y > best0.y) ? c : i0y;  best0.y = fmaxf(best0.y, v0.y);
        i0z = (v0.z > best0.z) ? c : i0z;  best0.z = fmaxf(best0.z, v0.z);
        i0w = (v0.w > best0.w) ? c : i0w;  best0.w = fmaxf(best0.w, v0.w);
        i1x = (v1.x > best1.x) ? c : i1x;  best1.x = fmaxf(best1.x, v1.x);
        i1y = (v1.y > best1.y) ? c : i1y;  best1.y = fmaxf(best1.y, v1.y);
        i1z = (v1.z > best1.z) ? c : i1z;  best1.z = fmaxf(best1.z, v1.z);
        i1w = (v1.w > best1.w) ? c : i1w;  best1.w = fmaxf(best1.w, v1.w);
        i2x = (v2.x > best2.x) ? c : i2x;  best2.x = fmaxf(best2.x, v2.x);
        i2y = (v2.y > best2.y) ? c : i2y;  best2.y = fmaxf(best2.y, v2.y);
        i2z = (v2.z > best2.z) ? c : i2z;  best2.z = fmaxf(best2.z, v2.z);
        i2w = (v2.w > best2.w) ? c : i2w;  best2.w = fmaxf(best2.w, v2.w);
        i3x = (v3.x > best3.x) ? c : i3x;  best3.x = fmaxf(best3.x, v3.x);
        i3y = (v3.y > best3.y) ? c : i3y;  best3.y = fmaxf(best3.y, v3.y);
        i3z = (v3.z > best3.z) ? c : i3z;  best3.z = fmaxf(best3.z, v3.z);
        i3w = (v3.w > best3.w) ? c : i3w;  best3.w = fmaxf(best3.w, v3.w);
    }

    atomicAdd(&hist[t0.x * CLASS_NUM + i0x], 1);
    atomicAdd(&hist[t0.y * CLASS_NUM + i0y], 1);
    atomicAdd(&hist[t0.z * CLASS_NUM + i0z], 1);
    atomicAdd(&hist[t0.w * CLASS_NUM + i0w], 1);
    atomicAdd(&hist[t1.x * CLASS_NUM + i1x], 1);
    atomicAdd(&hist[t1.y * CLASS_NUM + i1y], 1);
    atomicAdd(&hist[t1.z * CLASS_NUM + i1z], 1);
    atomicAdd(&hist[t1.w * CLASS_NUM + i1w], 1);
    atomicAdd(&hist[t2.x * CLASS_NUM + i2x], 1);
    atomicAdd(&hist[t2.y * CLASS_NUM + i2y], 1);
    atomicAdd(&hist[t2.z * CLASS_NUM + i2z], 1);
    atomicAdd(&hist[t2.w * CLASS_NUM + i2w], 1);
    atomicAdd(&hist[t3.x * CLASS_NUM + i3x], 1);
    atomicAdd(&hist[t3.y * CLASS_NUM + i3y], 1);
    atomicAdd(&hist[t3.z * CLASS_NUM + i3z], 1);
    atomicAdd(&hist[t3.w * CLASS_NUM + i3w], 1);

    __syncthreads();
    // Direct global accumulation: 361 atomics/block over 361 L2-resident
    // addresses (256-way contention per address) — microseconds, and it
    // removes both the 370 KB ws round-trip and the reduce dispatch.
    for (int i = threadIdx.x; i < NBINS; i += TPB) {
        const int v = hist[i];
        if (v) atomicAdd(&out[i], v);
    }
}

extern "C" void kernel_launch(void* const* d_in, const int* in_sizes, int n_in,
                              void* d_out, int out_size, void* d_ws, size_t ws_size,
                              hipStream_t stream) {
    const f4*   in  = (const f4*)d_in[0];
    const int4* tgt = (const int4*)d_in[1];
    int* out = (int*)d_out;
    (void)d_ws; (void)ws_size;   // deliberately unused — see note above

    zero_out_kernel<<<1, 384, 0, stream>>>(out);
    confusion_kernel<<<NBLK, TPB, 0, stream>>>(in, tgt, out);
}